// Round 1
// baseline (327.162 us; speedup 1.0000x reference)
//
#include <hip/hip_runtime.h>

// SelfAttention2d, B=8 C=256 H=W=64 (N=4096), Ck=32.
// out = gamma * (V (Q^T K)) + x  ==  gamma * ((V Q^T) K) + x  (associativity;
// softmax in the torch original is dead code, reproduced faithfully by ref).
// Fully collapsed to per-batch 256x256 Gram + tiny algebra + one 256x256 GEMM.

constexpr int NB = 8;
constexpr int NC = 256;
constexpr int NK = 32;    // C/8
constexpr int NN = 4096;  // H*W

typedef float  f32x4  __attribute__((ext_vector_type(4)));
typedef __bf16 bf16x8 __attribute__((ext_vector_type(8)));

__device__ __forceinline__ bf16x8 load_bf8(const float* __restrict__ p) {
  f32x4 a = *(const f32x4*)p;
  f32x4 b = *(const f32x4*)(p + 4);
  bf16x8 r;
  r[0] = (__bf16)a[0]; r[1] = (__bf16)a[1]; r[2] = (__bf16)a[2]; r[3] = (__bf16)a[3];
  r[4] = (__bf16)b[0]; r[5] = (__bf16)b[1]; r[6] = (__bf16)b[2]; r[7] = (__bf16)b[3];
  return r;
}

// ---------- kernel 1: xsum[b,c] = sum_n x[b,c,n] ----------
__global__ __launch_bounds__(64) void k_xsum(const float* __restrict__ x,
                                             float* __restrict__ xsum) {
  int row = blockIdx.x;  // b*NC + c
  const float* p = x + (size_t)row * NN;
  int t = threadIdx.x;
  float s = 0.f;
#pragma unroll
  for (int i = 0; i < 16; ++i) {
    f32x4 v = *(const f32x4*)(p + (i * 64 + t) * 4);
    s += v[0] + v[1] + v[2] + v[3];
  }
#pragma unroll
  for (int off = 32; off; off >>= 1) s += __shfl_down(s, off);
  if (t == 0) xsum[row] = s;
}

// ---------- kernel 2: Spart[ks][b] = X_b(:, ksplit) X_b(:, ksplit)^T ----------
// grid = NB * 16 * 2.  64x64 S-tile per block, 4 waves in 2x2 quadrants.
__global__ __launch_bounds__(256) void k_gram(const float* __restrict__ x,
                                              float* __restrict__ Spart) {
  int bid  = blockIdx.x;
  int ks   = bid & 1;
  int tile = (bid >> 1) & 15;
  int b    = bid >> 5;
  int tr = (tile >> 2) * 64, tc = (tile & 3) * 64;
  int lane = threadIdx.x & 63;
  int w    = threadIdx.x >> 6;
  int r0 = tr + (w >> 1) * 32;
  int c0 = tc + (w & 1) * 32;
  const float* xb = x + (size_t)b * NC * NN;
  int lr = lane & 15, lk = (lane >> 4) * 8;

  f32x4 acc[2][2] = {};
  for (int step = 0; step < 64; ++step) {
    int k0 = ks * 2048 + step * 32 + lk;
    bf16x8 a0 = load_bf8(xb + (size_t)(r0 + lr) * NN + k0);
    bf16x8 a1 = load_bf8(xb + (size_t)(r0 + 16 + lr) * NN + k0);
    bf16x8 b0 = load_bf8(xb + (size_t)(c0 + lr) * NN + k0);
    bf16x8 b1 = load_bf8(xb + (size_t)(c0 + 16 + lr) * NN + k0);
    acc[0][0] = __builtin_amdgcn_mfma_f32_16x16x32_bf16(a0, b0, acc[0][0], 0, 0, 0);
    acc[0][1] = __builtin_amdgcn_mfma_f32_16x16x32_bf16(a0, b1, acc[0][1], 0, 0, 0);
    acc[1][0] = __builtin_amdgcn_mfma_f32_16x16x32_bf16(a1, b0, acc[1][0], 0, 0, 0);
    acc[1][1] = __builtin_amdgcn_mfma_f32_16x16x32_bf16(a1, b1, acc[1][1], 0, 0, 0);
  }
  // C/D layout (16x16): col = lane&15, row = (lane>>4)*4 + j   [m89]
  int col = lane & 15, rowb = (lane >> 4) * 4;
  float* Sb = Spart + ((size_t)ks * NB + b) * NC * NC;
#pragma unroll
  for (int fa = 0; fa < 2; ++fa)
#pragma unroll
    for (int fb = 0; fb < 2; ++fb)
#pragma unroll
      for (int j = 0; j < 4; ++j) {
        int c1 = r0 + fa * 16 + rowb + j;
        int c2 = c0 + fb * 16 + col;
        Sb[c1 * NC + c2] = acc[fa][fb][j];
      }
}

// ---------- kernel 3: per-batch tiny algebra ----------
// T1 = S Wq^T + xsum bq^T ; M = Wv T1 + bv qsum^T ; G = M Wk ; h = M bk
// grid = NB, block = 1024 (16 waves)
__global__ __launch_bounds__(1024) void k_small(
    const float* __restrict__ Spart, const float* __restrict__ xsum,
    const float* __restrict__ Wq, const float* __restrict__ bq,
    const float* __restrict__ Wv, const float* __restrict__ bv,
    const float* __restrict__ Wk, const float* __restrict__ bk,
    float* __restrict__ Mw, float* __restrict__ G, float* __restrict__ h) {
  __shared__ float shT[NK][NC];  // T1 transposed [k][c]  (32 KB)
  __shared__ float shXs[NC];
  __shared__ float shQs[NK];
  int b = blockIdx.x;
  int t = threadIdx.x;
  const float* S0 = Spart + (size_t)b * NC * NC;
  const float* S1 = Spart + ((size_t)NB + b) * NC * NC;

  if (t < NC) shXs[t] = xsum[b * NC + t];
  __syncthreads();
  if (t < NK) {
    float s = 0.f;
    for (int c = 0; c < NC; ++c) s += Wq[t * NC + c] * shXs[c];
    shQs[t] = s + (float)NN * bq[t];
  }
  // --- T1 ---
  {
    int c = t & 255, kh = t >> 8;  // k = kh*8 .. kh*8+7
    float acc[8];
#pragma unroll
    for (int k = 0; k < 8; ++k) acc[k] = shXs[c] * bq[kh * 8 + k];
    for (int c4 = 0; c4 < NC / 4; ++c4) {
      f32x4 s4 = *(const f32x4*)&S0[c * NC + c4 * 4];
      f32x4 s4b = *(const f32x4*)&S1[c * NC + c4 * 4];
      s4[0] += s4b[0]; s4[1] += s4b[1]; s4[2] += s4b[2]; s4[3] += s4b[3];
#pragma unroll
      for (int k = 0; k < 8; ++k) {
        f32x4 w4 = *(const f32x4*)&Wq[(kh * 8 + k) * NC + c4 * 4];
        acc[k] += s4[0] * w4[0] + s4[1] * w4[1] + s4[2] * w4[2] + s4[3] * w4[3];
      }
    }
#pragma unroll
    for (int k = 0; k < 8; ++k) shT[kh * 8 + k][c] = acc[k];
  }
  __syncthreads();
  // --- M ---
  {
    int c = t & 255, kh = t >> 8;
    float acc[8];
    float bvc = bv[c];
#pragma unroll
    for (int k = 0; k < 8; ++k) acc[k] = bvc * shQs[kh * 8 + k];
    for (int c4 = 0; c4 < NC / 4; ++c4) {
      f32x4 w4 = *(const f32x4*)&Wv[c * NC + c4 * 4];
#pragma unroll
      for (int k = 0; k < 8; ++k) {
        f32x4 t4 = *(const f32x4*)&shT[kh * 8 + k][c4 * 4];
        acc[k] += w4[0] * t4[0] + w4[1] * t4[1] + w4[2] * t4[2] + w4[3] * t4[3];
      }
    }
#pragma unroll
    for (int k = 0; k < 8; ++k) Mw[((size_t)b * NC + c) * NK + kh * 8 + k] = acc[k];
  }
  __syncthreads();
  // --- G, h ---
  {
    int c1 = t & 255, ch = t >> 8;  // c2 block of 64
    float m[NK];
#pragma unroll
    for (int k4 = 0; k4 < NK / 4; ++k4) {
      f32x4 m4 = *(const f32x4*)&Mw[((size_t)b * NC + c1) * NK + k4 * 4];
      m[k4 * 4 + 0] = m4[0]; m[k4 * 4 + 1] = m4[1];
      m[k4 * 4 + 2] = m4[2]; m[k4 * 4 + 3] = m4[3];
    }
    float* Gb = G + (size_t)b * NC * NC;
    for (int c4 = 0; c4 < 16; ++c4) {
      int c2 = ch * 64 + c4 * 4;
      f32x4 g = {0.f, 0.f, 0.f, 0.f};
#pragma unroll
      for (int k = 0; k < NK; ++k) {
        f32x4 w4 = *(const f32x4*)&Wk[k * NC + c2];
        g[0] += m[k] * w4[0]; g[1] += m[k] * w4[1];
        g[2] += m[k] * w4[2]; g[3] += m[k] * w4[3];
      }
      *(f32x4*)&Gb[c1 * NC + c2] = g;
    }
    if (ch == 0) {
      float s = 0.f;
#pragma unroll
      for (int k = 0; k < NK; ++k) s += m[k] * bk[k];
      h[b * NC + c1] = s;
    }
  }
}

// ---------- kernel 4: out = gamma*(G X + h 1^T) + x ----------
// grid = NB * 64 (n-tiles of 64), block 256 (4 waves, each 64 rows x 64 cols)
__global__ __launch_bounds__(256) void k_out(
    const float* __restrict__ x, const float* __restrict__ G,
    const float* __restrict__ h, const float* __restrict__ gamma,
    float* __restrict__ out) {
  __shared__ __bf16 shX[64][40];  // [n][k], +8 pad keeps 16B align, breaks bank stride
  int bx = blockIdx.x;
  int b  = bx >> 6;
  int n0 = (bx & 63) * 64;
  int t = threadIdx.x;
  int lane = t & 63, w = t >> 6;
  int lr = lane & 15, lg = lane >> 4;
  const float* xb = x + (size_t)b * NC * NN;
  const float* Gb = G + (size_t)b * NC * NC;

  f32x4 acc[4][4] = {};
  for (int kk = 0; kk < 8; ++kk) {
    int k0 = kk * 32;
    {  // stage X[k0..k0+32)[n0..n0+64) -> shX[n][k] (bf16, transposed)
      int kr = t >> 3, n8 = (t & 7) * 8;
      const float* src = xb + (size_t)(k0 + kr) * NN + n0 + n8;
      f32x4 v0 = *(const f32x4*)src;
      f32x4 v1 = *(const f32x4*)(src + 4);
#pragma unroll
      for (int i = 0; i < 4; ++i) shX[n8 + i][kr] = (__bf16)v0[i];
#pragma unroll
      for (int i = 0; i < 4; ++i) shX[n8 + 4 + i][kr] = (__bf16)v1[i];
    }
    __syncthreads();
    bf16x8 afr[4];
#pragma unroll
    for (int fa = 0; fa < 4; ++fa) {
      int c1 = w * 64 + fa * 16 + lr;
      afr[fa] = load_bf8(Gb + (size_t)c1 * NC + k0 + lg * 8);
    }
#pragma unroll
    for (int fb = 0; fb < 4; ++fb) {
      bf16x8 bfr = *(const bf16x8*)&shX[fb * 16 + lr][lg * 8];
#pragma unroll
      for (int fa = 0; fa < 4; ++fa)
        acc[fa][fb] = __builtin_amdgcn_mfma_f32_16x16x32_bf16(afr[fa], bfr, acc[fa][fb], 0, 0, 0);
    }
    __syncthreads();
  }
  float g = gamma[0];
  int col = lane & 15, rowb = (lane >> 4) * 4;
#pragma unroll
  for (int fa = 0; fa < 4; ++fa) {
#pragma unroll
    for (int j = 0; j < 4; ++j) {
      int c1 = w * 64 + fa * 16 + rowb + j;
      float hc = h[b * NC + c1];
      size_t base = ((size_t)b * NC + c1) * NN + n0;
#pragma unroll
      for (int fb = 0; fb < 4; ++fb) {
        int n = fb * 16 + col;
        out[base + n] = g * (acc[fa][fb][j] + hc) + xb[(size_t)c1 * NN + n0 + n];
      }
    }
  }
}

extern "C" void kernel_launch(void* const* d_in, const int* in_sizes, int n_in,
                              void* d_out, int out_size, void* d_ws, size_t ws_size,
                              hipStream_t stream) {
  (void)in_sizes; (void)n_in; (void)out_size; (void)ws_size;
  const float* x     = (const float*)d_in[0];
  const float* Wk    = (const float*)d_in[1];
  const float* bk    = (const float*)d_in[2];
  const float* Wq    = (const float*)d_in[3];
  const float* bq    = (const float*)d_in[4];
  const float* Wv    = (const float*)d_in[5];
  const float* bv    = (const float*)d_in[6];
  const float* gamma = (const float*)d_in[7];
  float* out = (float*)d_out;

  float* Spart = (float*)d_ws;                       // 2 * NB*NC*NC
  float* G     = Spart + 2 * (size_t)NB * NC * NC;   // NB*NC*NC
  float* xs    = G + (size_t)NB * NC * NC;           // NB*NC
  float* h     = xs + NB * NC;                       // NB*NC
  float* Mw    = h + NB * NC;                        // NB*NC*NK

  k_xsum<<<NB * NC, 64, 0, stream>>>(x, xs);
  k_gram<<<NB * 16 * 2, 256, 0, stream>>>(x, Spart);
  k_small<<<NB, 1024, 0, stream>>>(Spart, xs, Wq, bq, Wv, bv, Wk, bk, Mw, G, h);
  k_out<<<NB * 64, 256, 0, stream>>>(x, G, h, gamma, out);
}

// Round 2
// 81.418 us; speedup vs baseline: 4.0183x; 4.0183x over previous
//
#include <hip/hip_runtime.h>

// SelfAttention2d, B=8 C=256 H=W=64 (N=4096), Ck=32, softmax dead code.
// out = gamma * (v q^T k) + x with q=Wq x+bq, k=Wk x+bk, v=Wv x+bv.
// Reassociated:
//   Q = Wq X + bq 1^T            (32 x N, never materialized)
//   T = X Q^T                    (256 x 32)   [front, n-chunked partials]
//   qsum = Q 1                   (32)
//   P = Wv T + bv qsum^T         (256 x 32)   [mid]
//   h = P bk                     (256)
//   out = gamma * (P (Wk X) + h 1^T) + X      [back, per n-tile]

constexpr int NB = 8;
constexpr int NC = 256;
constexpr int NK = 32;    // C/8
constexpr int NN = 4096;  // H*W
constexpr int NCHUNK = 32;  // front n-chunks (128 n each)

typedef float  f32x4  __attribute__((ext_vector_type(4)));
typedef __bf16 bf16x4 __attribute__((ext_vector_type(4)));
typedef __bf16 bf16x8 __attribute__((ext_vector_type(8)));

__device__ __forceinline__ bf16x8 load_bf8(const float* __restrict__ p) {
  f32x4 a = *(const f32x4*)p;
  f32x4 b = *(const f32x4*)(p + 4);
  bf16x8 r;
  r[0] = (__bf16)a[0]; r[1] = (__bf16)a[1]; r[2] = (__bf16)a[2]; r[3] = (__bf16)a[3];
  r[4] = (__bf16)b[0]; r[5] = (__bf16)b[1]; r[6] = (__bf16)b[2]; r[7] = (__bf16)b[3];
  return r;
}

// ---------------- front: Tpart[chunk][b] = X_chunk Q_chunk^T, qsum partials ----
// grid = NB*NCHUNK (256 blocks), 256 threads (4 waves). Chunk = 128 n = 2 subtiles.
__global__ __launch_bounds__(256) void k_front(
    const float* __restrict__ x, const float* __restrict__ Wq,
    const float* __restrict__ bq, __bf16* __restrict__ Tpart,
    float* __restrict__ qsum_part) {
  __shared__ __bf16 ldsT[64][264];  // x-subtile transposed [n][c], +8 pad
  __shared__ __bf16 ldsQ[64][36];   // Q^T subtile [n][j]
  __shared__ float  ldsQs[4][32];
  int bid = blockIdx.x;
  int b = bid >> 5, chunk = bid & 31;
  int t = threadIdx.x;
  int lane = t & 63, w = t >> 6, lr = lane & 15, lg = lane >> 4;
  const float* xb = x + (size_t)b * NC * NN;
  float bq0 = bq[lr], bq1 = bq[16 + lr];
  float qs0 = 0.f, qs1 = 0.f;
  f32x4 accT[4][2] = {};

  for (int s = 0; s < 2; ++s) {
    int nsub = chunk * 128 + s * 64;
    {  // stage x[0:256][nsub:nsub+64] -> ldsT[n][c] bf16 (4x4 register transpose)
      int c0 = (t & 63) * 4, nq = (t >> 6) * 4;
#pragma unroll
      for (int p = 0; p < 4; ++p) {
        int n = p * 16 + nq;
        f32x4 v0 = *(const f32x4*)(xb + (size_t)(c0 + 0) * NN + nsub + n);
        f32x4 v1 = *(const f32x4*)(xb + (size_t)(c0 + 1) * NN + nsub + n);
        f32x4 v2 = *(const f32x4*)(xb + (size_t)(c0 + 2) * NN + nsub + n);
        f32x4 v3 = *(const f32x4*)(xb + (size_t)(c0 + 3) * NN + nsub + n);
#pragma unroll
        for (int i = 0; i < 4; ++i) {
          bf16x4 wv = {(__bf16)v0[i], (__bf16)v1[i], (__bf16)v2[i], (__bf16)v3[i]};
          *(bf16x4*)&ldsT[n + i][c0] = wv;
        }
      }
    }
    __syncthreads();
    // Q^T(64x32) = x^T Wq^T : wave w owns n-rows [w*16, w*16+16)
    f32x4 aq[2] = {};
#pragma unroll
    for (int ks = 0; ks < 8; ++ks) {
      bf16x8 af = *(const bf16x8*)&ldsT[w * 16 + lr][ks * 32 + lg * 8];
      bf16x8 b0 = load_bf8(Wq + (size_t)lr * NC + ks * 32 + lg * 8);
      bf16x8 b1 = load_bf8(Wq + (size_t)(16 + lr) * NC + ks * 32 + lg * 8);
      aq[0] = __builtin_amdgcn_mfma_f32_16x16x32_bf16(af, b0, aq[0], 0, 0, 0);
      aq[1] = __builtin_amdgcn_mfma_f32_16x16x32_bf16(af, b1, aq[1], 0, 0, 0);
    }
#pragma unroll
    for (int r = 0; r < 4; ++r) { aq[0][r] += bq0; aq[1][r] += bq1; }
    qs0 += aq[0][0] + aq[0][1] + aq[0][2] + aq[0][3];
    qs1 += aq[1][0] + aq[1][1] + aq[1][2] + aq[1][3];
#pragma unroll
    for (int q = 0; q < 2; ++q)
#pragma unroll
      for (int r = 0; r < 4; ++r)
        ldsQ[w * 16 + lg * 4 + r][q * 16 + lr] = (__bf16)aq[q][r];
    __syncthreads();
    // T(256x32) += x Q^T : a-frags straight from global (L2-hot), b from ldsQ
#pragma unroll
    for (int ks2 = 0; ks2 < 2; ++ks2) {
      bf16x8 bf0, bf1;
#pragma unroll
      for (int i = 0; i < 8; ++i) {
        bf0[i] = ldsQ[ks2 * 32 + lg * 8 + i][lr];
        bf1[i] = ldsQ[ks2 * 32 + lg * 8 + i][16 + lr];
      }
#pragma unroll
      for (int mt = 0; mt < 4; ++mt) {
        int c = w * 64 + mt * 16 + lr;
        bf16x8 af = load_bf8(xb + (size_t)c * NN + nsub + ks2 * 32 + lg * 8);
        accT[mt][0] = __builtin_amdgcn_mfma_f32_16x16x32_bf16(af, bf0, accT[mt][0], 0, 0, 0);
        accT[mt][1] = __builtin_amdgcn_mfma_f32_16x16x32_bf16(af, bf1, accT[mt][1], 0, 0, 0);
      }
    }
  }
  // qsum partial: reduce over row-groups then waves
  qs0 += __shfl_xor(qs0, 16); qs0 += __shfl_xor(qs0, 32);
  qs1 += __shfl_xor(qs1, 16); qs1 += __shfl_xor(qs1, 32);
  if (lane < 16) { ldsQs[w][lane] = qs0; ldsQs[w][16 + lane] = qs1; }
  __syncthreads();
  if (t < 32)
    qsum_part[(size_t)(chunk * NB + b) * NK + t] =
        ldsQs[0][t] + ldsQs[1][t] + ldsQs[2][t] + ldsQs[3][t];
  // Tpart write (bf16)
  __bf16* Tp = Tpart + (size_t)(chunk * NB + b) * NC * NK;
#pragma unroll
  for (int mt = 0; mt < 4; ++mt)
#pragma unroll
    for (int q = 0; q < 2; ++q)
#pragma unroll
      for (int r = 0; r < 4; ++r) {
        int c = w * 64 + mt * 16 + lg * 4 + r;
        Tp[(size_t)c * NK + q * 16 + lr] = (__bf16)accT[mt][q][r];
      }
}

// ---------------- mid: reduce Tpart -> T; P = Wv T + bv qsum^T; h = P bk -------
// grid = NB (8 blocks), 256 threads
__global__ __launch_bounds__(256) void k_mid(
    const __bf16* __restrict__ Tpart, const float* __restrict__ qsum_part,
    const float* __restrict__ Wv, const float* __restrict__ bv,
    const float* __restrict__ bk, __bf16* __restrict__ P,
    float* __restrict__ h) {
  __shared__ __bf16 shTt[NK][264];  // T transposed [j][c], +8 pad
  __shared__ float shQsum[NK];
  int b = blockIdx.x, t = threadIdx.x;
  if (t < NK) {
    float s = 0.f;
    for (int ch = 0; ch < NCHUNK; ++ch) s += qsum_part[(size_t)(ch * NB + b) * NK + t];
    shQsum[t] = s;
  }
  // coalesced partial-sum reduction: thread t owns elems idx = rep*1024 + t*4
  float acc[8][4] = {};
  for (int ch = 0; ch < NCHUNK; ++ch) {
    const __bf16* base = Tpart + (size_t)(ch * NB + b) * NC * NK;
#pragma unroll
    for (int rep = 0; rep < 8; ++rep) {
      bf16x4 v = *(const bf16x4*)(base + rep * 1024 + t * 4);
#pragma unroll
      for (int i = 0; i < 4; ++i) acc[rep][i] += (float)v[i];
    }
  }
  {
    int c_lo = t >> 3, j0 = (t & 7) * 4;
#pragma unroll
    for (int rep = 0; rep < 8; ++rep)
#pragma unroll
      for (int i = 0; i < 4; ++i)
        shTt[j0 + i][rep * 32 + c_lo] = (__bf16)acc[rep][i];
  }
  __syncthreads();
  // P = Wv T + bv qsum^T via MFMA
  int lane = t & 63, w = t >> 6, lr = lane & 15, lg = lane >> 4;
  float bk0 = bk[lr], bk1 = bk[16 + lr];
  f32x4 accP[4][2] = {};
#pragma unroll
  for (int ks = 0; ks < 8; ++ks) {
    bf16x8 b0 = *(const bf16x8*)&shTt[lr][ks * 32 + lg * 8];
    bf16x8 b1 = *(const bf16x8*)&shTt[16 + lr][ks * 32 + lg * 8];
#pragma unroll
    for (int mt = 0; mt < 4; ++mt) {
      int c = w * 64 + mt * 16 + lr;
      bf16x8 af = load_bf8(Wv + (size_t)c * NC + ks * 32 + lg * 8);
      accP[mt][0] = __builtin_amdgcn_mfma_f32_16x16x32_bf16(af, b0, accP[mt][0], 0, 0, 0);
      accP[mt][1] = __builtin_amdgcn_mfma_f32_16x16x32_bf16(af, b1, accP[mt][1], 0, 0, 0);
    }
  }
#pragma unroll
  for (int mt = 0; mt < 4; ++mt) {
    float hacc[4] = {0.f, 0.f, 0.f, 0.f};
#pragma unroll
    for (int q = 0; q < 2; ++q) {
      float bkj = q ? bk1 : bk0;
      float qs = shQsum[q * 16 + lr];
#pragma unroll
      for (int r = 0; r < 4; ++r) {
        int c = w * 64 + mt * 16 + lg * 4 + r;
        float val = accP[mt][q][r] + bv[c] * qs;
        P[((size_t)b * NC + c) * NK + q * 16 + lr] = (__bf16)val;
        hacc[r] += val * bkj;
      }
    }
#pragma unroll
    for (int r = 0; r < 4; ++r) {
      float v = hacc[r];
      v += __shfl_xor(v, 1); v += __shfl_xor(v, 2);
      v += __shfl_xor(v, 4); v += __shfl_xor(v, 8);
      if (lr == 0) h[b * NC + w * 64 + mt * 16 + lg * 4 + r] = v;
    }
  }
}

// ---------------- back: out = gamma*(P (Wk X) + h 1^T) + x ---------------------
// grid = NB*64 (n-tiles of 64), 256 threads (4 waves)
__global__ __launch_bounds__(256) void k_back(
    const float* __restrict__ x, const __bf16* __restrict__ P,
    const float* __restrict__ h, const float* __restrict__ Wk,
    const float* __restrict__ gamma, float* __restrict__ out) {
  __shared__ __bf16 ldsT[64][264];  // x-tile transposed [n][c]
  __shared__ __bf16 ldsK[64][40];   // K^T tile [n][j], pad->80B rows (16B-aligned)
  int bid = blockIdx.x;
  int b = bid >> 6, n0 = (bid & 63) * 64;
  int t = threadIdx.x;
  int lane = t & 63, w = t >> 6, lr = lane & 15, lg = lane >> 4;
  const float* xb = x + (size_t)b * NC * NN;
  {  // stage
    int c0 = (t & 63) * 4, nq = (t >> 6) * 4;
#pragma unroll
    for (int p = 0; p < 4; ++p) {
      int n = p * 16 + nq;
      f32x4 v0 = *(const f32x4*)(xb + (size_t)(c0 + 0) * NN + n0 + n);
      f32x4 v1 = *(const f32x4*)(xb + (size_t)(c0 + 1) * NN + n0 + n);
      f32x4 v2 = *(const f32x4*)(xb + (size_t)(c0 + 2) * NN + n0 + n);
      f32x4 v3 = *(const f32x4*)(xb + (size_t)(c0 + 3) * NN + n0 + n);
#pragma unroll
      for (int i = 0; i < 4; ++i) {
        bf16x4 wv = {(__bf16)v0[i], (__bf16)v1[i], (__bf16)v2[i], (__bf16)v3[i]};
        *(bf16x4*)&ldsT[n + i][c0] = wv;
      }
    }
  }
  __syncthreads();
  // K^T(64x32) = x^T Wk^T (no bias; bk folded into h)
  f32x4 ak[2] = {};
#pragma unroll
  for (int ks = 0; ks < 8; ++ks) {
    bf16x8 af = *(const bf16x8*)&ldsT[w * 16 + lr][ks * 32 + lg * 8];
    bf16x8 b0 = load_bf8(Wk + (size_t)lr * NC + ks * 32 + lg * 8);
    bf16x8 b1 = load_bf8(Wk + (size_t)(16 + lr) * NC + ks * 32 + lg * 8);
    ak[0] = __builtin_amdgcn_mfma_f32_16x16x32_bf16(af, b0, ak[0], 0, 0, 0);
    ak[1] = __builtin_amdgcn_mfma_f32_16x16x32_bf16(af, b1, ak[1], 0, 0, 0);
  }
#pragma unroll
  for (int q = 0; q < 2; ++q)
#pragma unroll
    for (int r = 0; r < 4; ++r)
      ldsK[w * 16 + lg * 4 + r][q * 16 + lr] = (__bf16)ak[q][r];
  __syncthreads();
  // out-tile(256x64) = P Kt  (K=32: single MFMA step)
  f32x4 acc[4][4] = {};
  bf16x8 bfr[4];
#pragma unroll
  for (int ft = 0; ft < 4; ++ft)
    bfr[ft] = *(const bf16x8*)&ldsK[ft * 16 + lr][lg * 8];
#pragma unroll
  for (int mt = 0; mt < 4; ++mt) {
    int c = w * 64 + mt * 16 + lr;
    bf16x8 af = *(const bf16x8*)(P + ((size_t)b * NC + c) * NK + lg * 8);
#pragma unroll
    for (int ft = 0; ft < 4; ++ft)
      acc[mt][ft] = __builtin_amdgcn_mfma_f32_16x16x32_bf16(af, bfr[ft], acc[mt][ft], 0, 0, 0);
  }
  float g = gamma[0];
#pragma unroll
  for (int mt = 0; mt < 4; ++mt)
#pragma unroll
    for (int r = 0; r < 4; ++r) {
      int c = w * 64 + mt * 16 + lg * 4 + r;
      float hc = h[b * NC + c];
      const float* xr = xb + (size_t)c * NN + n0;
      float* orow = out + ((size_t)b * NC + c) * NN + n0;
#pragma unroll
      for (int ft = 0; ft < 4; ++ft) {
        int n = ft * 16 + lr;
        orow[n] = g * (acc[mt][ft][r] + hc) + xr[n];
      }
    }
}

extern "C" void kernel_launch(void* const* d_in, const int* in_sizes, int n_in,
                              void* d_out, int out_size, void* d_ws, size_t ws_size,
                              hipStream_t stream) {
  (void)in_sizes; (void)n_in; (void)out_size; (void)ws_size;
  const float* x     = (const float*)d_in[0];
  const float* Wk    = (const float*)d_in[1];
  const float* bk    = (const float*)d_in[2];
  const float* Wq    = (const float*)d_in[3];
  const float* bq    = (const float*)d_in[4];
  const float* Wv    = (const float*)d_in[5];
  const float* bv    = (const float*)d_in[6];
  const float* gamma = (const float*)d_in[7];
  float* out = (float*)d_out;

  char* wsb = (char*)d_ws;
  __bf16* Tpart     = (__bf16*)wsb;                          // 4 MB
  float*  qsum_part = (float*)(wsb + (4u << 20));            // 32 KB
  __bf16* P         = (__bf16*)(wsb + (4u << 20) + (32u << 10));   // 128 KB
  float*  h         = (float*)(wsb + (4u << 20) + (160u << 10));   // 8 KB

  k_front<<<NB * NCHUNK, 256, 0, stream>>>(x, Wq, bq, Tpart, qsum_part);
  k_mid<<<NB, 256, 0, stream>>>(Tpart, qsum_part, Wv, bv, bk, P, h);
  k_back<<<NB * 64, 256, 0, stream>>>(x, P, h, Wk, gamma, out);
}

// Round 3
// 64.424 us; speedup vs baseline: 5.0783x; 1.2638x over previous
//
#include <hip/hip_runtime.h>

// SelfAttention2d, B=8 C=256 H=W=64 (N=4096), Ck=32, softmax dead code.
// out = gamma * (v q^T k) + x, reassociated:
//   Qt = X^T Wq^T + 1 bq^T      (N x 32, per-tile, LDS only)
//   Kt_t = X^T Wk^T             (N x 32, bf16, ws; bk folded into h)
//   T  = X Qt                   (256 x 32) n-chunked partials -> ws
//   qsum = Qt^T 1               (32)
//   P  = Wv T + bv qsum^T       (256 x 32), h = P bk
//   out = gamma * (P Kt + h 1^T) + x   [back: pure streaming, no LDS]

constexpr int NB = 8;
constexpr int NC = 256;
constexpr int NK = 32;     // C/8
constexpr int NN = 4096;   // H*W
constexpr int NCHUNK = 32; // front n-chunks (128 n each, 2 subtiles of 64)

typedef float  f32x4  __attribute__((ext_vector_type(4)));
typedef __bf16 bf16x4 __attribute__((ext_vector_type(4)));
typedef __bf16 bf16x8 __attribute__((ext_vector_type(8)));

__device__ __forceinline__ bf16x8 load_bf8(const float* __restrict__ p) {
  f32x4 a = *(const f32x4*)p;
  f32x4 b = *(const f32x4*)(p + 4);
  bf16x8 r;
  r[0] = (__bf16)a[0]; r[1] = (__bf16)a[1]; r[2] = (__bf16)a[2]; r[3] = (__bf16)a[3];
  r[4] = (__bf16)b[0]; r[5] = (__bf16)b[1]; r[6] = (__bf16)b[2]; r[7] = (__bf16)b[3];
  return r;
}

// ---------------- front: Qt/Kt per subtile; T partials; qsum partials ---------
// grid = NB*NCHUNK (256 blocks), 256 threads (4 waves), 2 serial 64-n subtiles.
__global__ __launch_bounds__(256) void k_front(
    const float* __restrict__ x, const float* __restrict__ Wq,
    const float* __restrict__ bq, const float* __restrict__ Wk,
    __bf16* __restrict__ Tpart, __bf16* __restrict__ Kt_t,
    float* __restrict__ qsum_part) {
  __shared__ __bf16 ldsT[64][264];   // x-subtile transposed [n][c]
  __shared__ __bf16 ldsQt[32][72];   // Q^T subtile [j][n]
  __shared__ float  ldsQs[4][32];
  int bid = blockIdx.x;
  int b = bid >> 5, chunk = bid & 31;
  int t = threadIdx.x;
  int lane = t & 63, w = t >> 6, lr = lane & 15, lg = lane >> 4;
  const float* xb = x + (size_t)b * NC * NN;
  float bq0 = bq[lr], bq1 = bq[16 + lr];
  float qs0 = 0.f, qs1 = 0.f;
  f32x4 accT[4][2] = {};

  for (int s = 0; s < 2; ++s) {
    int nsub = chunk * 128 + s * 64;
    {  // stage x[0:256][nsub:nsub+64] -> ldsT[n][c] bf16 (4x4 register transpose)
      int c0 = (t & 63) * 4, nq = (t >> 6) * 4;
#pragma unroll
      for (int p = 0; p < 4; ++p) {
        int n = p * 16 + nq;
        f32x4 v0 = *(const f32x4*)(xb + (size_t)(c0 + 0) * NN + nsub + n);
        f32x4 v1 = *(const f32x4*)(xb + (size_t)(c0 + 1) * NN + nsub + n);
        f32x4 v2 = *(const f32x4*)(xb + (size_t)(c0 + 2) * NN + nsub + n);
        f32x4 v3 = *(const f32x4*)(xb + (size_t)(c0 + 3) * NN + nsub + n);
#pragma unroll
        for (int i = 0; i < 4; ++i) {
          bf16x4 wv = {(__bf16)v0[i], (__bf16)v1[i], (__bf16)v2[i], (__bf16)v3[i]};
          *(bf16x4*)&ldsT[n + i][c0] = wv;
        }
      }
    }
    __syncthreads();
    // Qt(64x32) and Kt(64x32): A = x^T from ldsT (shared), B = Wq/Wk rows
    f32x4 aq[2] = {}, ak[2] = {};
#pragma unroll
    for (int ks = 0; ks < 8; ++ks) {
      bf16x8 af = *(const bf16x8*)&ldsT[w * 16 + lr][ks * 32 + lg * 8];
      bf16x8 q0 = load_bf8(Wq + (size_t)lr * NC + ks * 32 + lg * 8);
      bf16x8 q1 = load_bf8(Wq + (size_t)(16 + lr) * NC + ks * 32 + lg * 8);
      bf16x8 k0 = load_bf8(Wk + (size_t)lr * NC + ks * 32 + lg * 8);
      bf16x8 k1 = load_bf8(Wk + (size_t)(16 + lr) * NC + ks * 32 + lg * 8);
      aq[0] = __builtin_amdgcn_mfma_f32_16x16x32_bf16(af, q0, aq[0], 0, 0, 0);
      aq[1] = __builtin_amdgcn_mfma_f32_16x16x32_bf16(af, q1, aq[1], 0, 0, 0);
      ak[0] = __builtin_amdgcn_mfma_f32_16x16x32_bf16(af, k0, ak[0], 0, 0, 0);
      ak[1] = __builtin_amdgcn_mfma_f32_16x16x32_bf16(af, k1, ak[1], 0, 0, 0);
    }
#pragma unroll
    for (int r = 0; r < 4; ++r) { aq[0][r] += bq0; aq[1][r] += bq1; }
    qs0 += aq[0][0] + aq[0][1] + aq[0][2] + aq[0][3];
    qs1 += aq[1][0] + aq[1][1] + aq[1][2] + aq[1][3];
    // Kt_t[b][n][j] global (bf16 scalar stores; 32B segments across lanes)
    {
      int nrow = nsub + w * 16 + lg * 4;
#pragma unroll
      for (int q = 0; q < 2; ++q)
#pragma unroll
        for (int r = 0; r < 4; ++r)
          Kt_t[((size_t)b * NN + nrow + r) * NK + q * 16 + lr] = (__bf16)ak[q][r];
    }
    // ldsQt[j][n_local]
    {
      bf16x4 p0 = {(__bf16)aq[0][0], (__bf16)aq[0][1], (__bf16)aq[0][2], (__bf16)aq[0][3]};
      bf16x4 p1 = {(__bf16)aq[1][0], (__bf16)aq[1][1], (__bf16)aq[1][2], (__bf16)aq[1][3]};
      *(bf16x4*)&ldsQt[lr][w * 16 + lg * 4] = p0;
      *(bf16x4*)&ldsQt[16 + lr][w * 16 + lg * 4] = p1;
    }
    __syncthreads();
    // T(256x32) += X Qt : A = x rows from global (L1/L2-hot), B = ldsQt rows
#pragma unroll
    for (int ks2 = 0; ks2 < 2; ++ks2) {
      bf16x8 bf0 = *(const bf16x8*)&ldsQt[lr][ks2 * 32 + lg * 8];
      bf16x8 bf1 = *(const bf16x8*)&ldsQt[16 + lr][ks2 * 32 + lg * 8];
#pragma unroll
      for (int mt = 0; mt < 4; ++mt) {
        int c = w * 64 + mt * 16 + lr;
        bf16x8 af = load_bf8(xb + (size_t)c * NN + nsub + ks2 * 32 + lg * 8);
        accT[mt][0] = __builtin_amdgcn_mfma_f32_16x16x32_bf16(af, bf0, accT[mt][0], 0, 0, 0);
        accT[mt][1] = __builtin_amdgcn_mfma_f32_16x16x32_bf16(af, bf1, accT[mt][1], 0, 0, 0);
      }
    }
  }
  // qsum partial
  qs0 += __shfl_xor(qs0, 16); qs0 += __shfl_xor(qs0, 32);
  qs1 += __shfl_xor(qs1, 16); qs1 += __shfl_xor(qs1, 32);
  if (lane < 16) { ldsQs[w][lane] = qs0; ldsQs[w][16 + lane] = qs1; }
  __syncthreads();
  if (t < 32)
    qsum_part[(size_t)(chunk * NB + b) * NK + t] =
        ldsQs[0][t] + ldsQs[1][t] + ldsQs[2][t] + ldsQs[3][t];
  // Tpart[chunk][b][j][c] bf16 (D rows c are lane-consecutive -> bf16x4 packs)
  __bf16* Tp = Tpart + (size_t)(chunk * NB + b) * NC * NK;
#pragma unroll
  for (int mt = 0; mt < 4; ++mt)
#pragma unroll
    for (int jf = 0; jf < 2; ++jf) {
      bf16x4 pk = {(__bf16)accT[mt][jf][0], (__bf16)accT[mt][jf][1],
                   (__bf16)accT[mt][jf][2], (__bf16)accT[mt][jf][3]};
      *(bf16x4*)&Tp[(jf * 16 + lr) * NC + w * 64 + mt * 16 + lg * 4] = pk;
    }
}

// ---------------- mid: reduce Tpart -> T; P = Wv T + bv qsum^T; h = P bk ------
// grid = NB (8 blocks), 256 threads
__global__ __launch_bounds__(256) void k_mid(
    const __bf16* __restrict__ Tpart, const float* __restrict__ qsum_part,
    const float* __restrict__ Wv, const float* __restrict__ bv,
    const float* __restrict__ bk, __bf16* __restrict__ P,
    float* __restrict__ h) {
  __shared__ __bf16 shTt[NK][264];  // T transposed [j][c]
  __shared__ float shQsum[NK];
  int b = blockIdx.x, t = threadIdx.x;
  if (t < NK) {
    float s = 0.f;
#pragma unroll 8
    for (int ch = 0; ch < NCHUNK; ++ch) s += qsum_part[(size_t)(ch * NB + b) * NK + t];
    shQsum[t] = s;
  }
  // coalesced partial-sum: thread t owns flat elems rep*1024 + t*4 of [j][c]
  float acc[8][4] = {};
#pragma unroll 4
  for (int ch = 0; ch < NCHUNK; ++ch) {
    const __bf16* base = Tpart + (size_t)(ch * NB + b) * NC * NK;
#pragma unroll
    for (int rep = 0; rep < 8; ++rep) {
      bf16x4 v = *(const bf16x4*)(base + rep * 1024 + t * 4);
#pragma unroll
      for (int i = 0; i < 4; ++i) acc[rep][i] += (float)v[i];
    }
  }
  {
    int j_hi = t >> 6, c0 = (t & 63) * 4;
#pragma unroll
    for (int rep = 0; rep < 8; ++rep) {
      bf16x4 pk = {(__bf16)acc[rep][0], (__bf16)acc[rep][1],
                   (__bf16)acc[rep][2], (__bf16)acc[rep][3]};
      *(bf16x4*)&shTt[rep * 4 + j_hi][c0] = pk;
    }
  }
  __syncthreads();
  // P = Wv T + bv qsum^T via MFMA; h = P bk
  int lane = t & 63, w = t >> 6, lr = lane & 15, lg = lane >> 4;
  float bk0 = bk[lr], bk1 = bk[16 + lr];
  f32x4 accP[4][2] = {};
#pragma unroll
  for (int ks = 0; ks < 8; ++ks) {
    bf16x8 b0 = *(const bf16x8*)&shTt[lr][ks * 32 + lg * 8];
    bf16x8 b1 = *(const bf16x8*)&shTt[16 + lr][ks * 32 + lg * 8];
#pragma unroll
    for (int mt = 0; mt < 4; ++mt) {
      int c = w * 64 + mt * 16 + lr;
      bf16x8 af = load_bf8(Wv + (size_t)c * NC + ks * 32 + lg * 8);
      accP[mt][0] = __builtin_amdgcn_mfma_f32_16x16x32_bf16(af, b0, accP[mt][0], 0, 0, 0);
      accP[mt][1] = __builtin_amdgcn_mfma_f32_16x16x32_bf16(af, b1, accP[mt][1], 0, 0, 0);
    }
  }
#pragma unroll
  for (int mt = 0; mt < 4; ++mt) {
    float hacc[4] = {0.f, 0.f, 0.f, 0.f};
#pragma unroll
    for (int q = 0; q < 2; ++q) {
      float bkj = q ? bk1 : bk0;
      float qs = shQsum[q * 16 + lr];
#pragma unroll
      for (int r = 0; r < 4; ++r) {
        int c = w * 64 + mt * 16 + lg * 4 + r;
        float val = accP[mt][q][r] + bv[c] * qs;
        P[((size_t)b * NC + c) * NK + q * 16 + lr] = (__bf16)val;
        hacc[r] += val * bkj;
      }
    }
#pragma unroll
    for (int r = 0; r < 4; ++r) {
      float v = hacc[r];
      v += __shfl_xor(v, 1); v += __shfl_xor(v, 2);
      v += __shfl_xor(v, 4); v += __shfl_xor(v, 8);
      if (lr == 0) h[b * NC + w * 64 + mt * 16 + lg * 4 + r] = v;
    }
  }
}

// ---------------- back: out = gamma*(P Kt + h 1^T) + x -----------------------
// D[n][c] orientation: A = Kt_t[n][j] (global, contiguous), B = P[c][j] rows.
// grid = NB*64 (n-tiles of 64), 256 threads (4 waves), NO LDS, NO syncs.
__global__ __launch_bounds__(256) void k_back(
    const float* __restrict__ x, const __bf16* __restrict__ Kt_t,
    const __bf16* __restrict__ P, const float* __restrict__ h,
    const float* __restrict__ gamma, float* __restrict__ out) {
  int bid = blockIdx.x;
  int b = bid >> 6, n0 = (bid & 63) * 64;
  int t = threadIdx.x;
  int lane = t & 63, w = t >> 6, lr = lane & 15, lg = lane >> 4;

  bf16x8 af = *(const bf16x8*)&Kt_t[((size_t)b * NN + n0 + w * 16 + lr) * NK + lg * 8];
  const __bf16* Pb = P + (size_t)b * NC * NK;
  f32x4 acc[16];
#pragma unroll
  for (int ft = 0; ft < 16; ++ft) {
    bf16x8 bfr = *(const bf16x8*)&Pb[(size_t)(ft * 16 + lr) * NK + lg * 8];
    f32x4 z = {0.f, 0.f, 0.f, 0.f};
    acc[ft] = __builtin_amdgcn_mfma_f32_16x16x32_bf16(af, bfr, z, 0, 0, 0);
  }
  float g = gamma[0];
  const float* hb = h + (size_t)b * NC;
#pragma unroll
  for (int ft = 0; ft < 16; ++ft) {
    int c = ft * 16 + lr;
    float hc = hb[c];
    size_t idx = ((size_t)b * NC + c) * NN + n0 + w * 16 + lg * 4;
    f32x4 xv = *(const f32x4*)&x[idx];
    f32x4 o;
#pragma unroll
    for (int r = 0; r < 4; ++r) o[r] = g * (acc[ft][r] + hc) + xv[r];
    *(f32x4*)&out[idx] = o;
  }
}

extern "C" void kernel_launch(void* const* d_in, const int* in_sizes, int n_in,
                              void* d_out, int out_size, void* d_ws, size_t ws_size,
                              hipStream_t stream) {
  (void)in_sizes; (void)n_in; (void)out_size; (void)ws_size;
  const float* x     = (const float*)d_in[0];
  const float* Wk    = (const float*)d_in[1];
  const float* bk    = (const float*)d_in[2];
  const float* Wq    = (const float*)d_in[3];
  const float* bq    = (const float*)d_in[4];
  const float* Wv    = (const float*)d_in[5];
  const float* bv    = (const float*)d_in[6];
  const float* gamma = (const float*)d_in[7];
  float* out = (float*)d_out;

  char* wsb = (char*)d_ws;
  __bf16* Tpart     = (__bf16*)wsb;                                 // 4 MB
  __bf16* Kt_t      = (__bf16*)(wsb + (4u << 20));                  // 2 MB
  float*  qsum_part = (float*)(wsb + (6u << 20));                   // 32 KB
  __bf16* P         = (__bf16*)(wsb + (6u << 20) + (32u << 10));    // 16 KB
  float*  h         = (float*)(wsb + (6u << 20) + (48u << 10));     // 8 KB

  k_front<<<NB * NCHUNK, 256, 0, stream>>>(x, Wq, bq, Wk, Tpart, Kt_t, qsum_part);
  k_mid<<<NB, 256, 0, stream>>>(Tpart, qsum_part, Wv, bv, bk, P, h);
  k_back<<<NB * 64, 256, 0, stream>>>(x, Kt_t, P, h, gamma, out);
}